// Round 6
// baseline (400.573 us; speedup 1.0000x reference)
//
#include <hip/hip_runtime.h>
#include <hip/hip_bf16.h>

#define B_ROWS 131072
#define TWO_PI_F 6.28318530717958647692f

// Output layout (float32 element offsets into d_out):
//   model_output [131072,3] @0 | top_outputs @393216 | selection_indices @786432
//   selection_logits @917504 (1.0f) | selection_probabilities @9306112 (1/64)
#define OUT_TOP    393216
#define OUT_SEL    786432
#define OUT_LOGITS 917504
#define OUT_PROBS  9306112

// Workspace layout (int32 element offsets):
#define WS_SEL    0          // sel[131072]
#define WS_BLK    131072     // per-block hist -> scatter bases [512*64]
#define WS_ROWS   163840     // padded rowsArr[135168], memset to -1
#define WS_GMOD   299008     // groupModel[2112], memset to -1
#define WS_TOT    301120     // per-model totals [64], memset to 0
#define NGRP_MAX  2112

typedef float vfloat4 __attribute__((ext_vector_type(4)));

// ---------------- k_prep: selection + per-block hist + model totals + constant fills ----
__global__ __launch_bounds__(256) void k_prep(const float* __restrict__ in,
                                              float* __restrict__ out,
                                              int* __restrict__ sel,
                                              int* __restrict__ blkCnt,
                                              int* __restrict__ tot) {
    __shared__ int hist[64];
    const int tid = threadIdx.x, bid = blockIdx.x;
    if (tid < 64) hist[tid] = 0;
    __syncthreads();

    const int r = bid * 256 + tid;  // grid is exactly 512x256 = 131072
    const float xx = in[r * 6 + 0];
    const float zz = in[r * 6 + 2];
    float a = atan2f(zz, xx);
    a = fmodf(a + TWO_PI_F, TWO_PI_F);
    const float t = a / TWO_PI_F * 64.0f;   // keep exact op order (boundary-sensitive)
    int s = (int)floorf(t);
    s = s < 0 ? 0 : (s > 63 ? 63 : s);
    sel[r] = s;
    out[OUT_SEL + r] = (float)s;
    atomicAdd(&hist[s], 1);

    // constant fills, nontemporal (no L2 pollution)
    {
        vfloat4* lg = (vfloat4*)(out + OUT_LOGITS);
        vfloat4* pb = (vfloat4*)(out + OUT_PROBS);
        const vfloat4 ones = {1.f, 1.f, 1.f, 1.f};
        const vfloat4 pr = {0.015625f, 0.015625f, 0.015625f, 0.015625f};
#pragma unroll
        for (int k = 0; k < 16; ++k) {
            __builtin_nontemporal_store(ones, lg + r + k * B_ROWS);
            __builtin_nontemporal_store(pr, pb + r + k * B_ROWS);
        }
    }

    __syncthreads();
    if (tid < 64) {
        blkCnt[bid * 64 + tid] = hist[tid];
        atomicAdd(&tot[tid], hist[tid]);
    }
}

// ---------------- k_scanwrite: 64 blocks (1 wave each), block m handles model m -------
// Computes padded per-model bases, fills gmodel, and converts blkCnt counts ->
// per-(block,model) scatter bases via a wave-parallel segmented prefix sum.
__global__ __launch_bounds__(64) void k_scanwrite(int* __restrict__ blkCnt,
                                                  const int* __restrict__ tot,
                                                  int* __restrict__ gmodel) {
    const int lane = threadIdx.x;
    const int bm = blockIdx.x;

    const int t = tot[lane];
    const int grp = (t + 63) >> 6;
    // inclusive scan of grp across the wave
    int inc = grp;
#pragma unroll
    for (int off = 1; off < 64; off <<= 1) {
        const int n = __shfl_up(inc, off, 64);
        if (lane >= off) inc += n;
    }
    const int exg = inc - grp;                 // exclusive group prefix per lane
    const int offG = __shfl(exg, bm, 64);      // this model's group offset
    const int myGrp = __shfl(grp, bm, 64);
    const int padBase = offG << 6;

    for (int i = lane; i < myGrp; i += 64) gmodel[offG + i] = bm;

    // segmented prefix over 512 block-counts for model bm; lane covers b in [8l, 8l+8)
    int c[8];
    int s = 0;
#pragma unroll
    for (int j = 0; j < 8; ++j) c[j] = blkCnt[(lane * 8 + j) * 64 + bm];
#pragma unroll
    for (int j = 0; j < 8; ++j) { const int v = c[j]; c[j] = s; s += v; }
    int incs = s;
#pragma unroll
    for (int off = 1; off < 64; off <<= 1) {
        const int n = __shfl_up(incs, off, 64);
        if (lane >= off) incs += n;
    }
    const int exs = incs - s;
#pragma unroll
    for (int j = 0; j < 8; ++j) blkCnt[(lane * 8 + j) * 64 + bm] = padBase + exs + c[j];
}

// ---------------- k_scatter: per-block reserved ranges, LDS atomics only ----------------
__global__ __launch_bounds__(256) void k_scatter(const int* __restrict__ sel,
                                                 const int* __restrict__ blkBase,
                                                 int* __restrict__ rowsArr) {
    __shared__ int cur[64];
    const int tid = threadIdx.x, bid = blockIdx.x;
    if (tid < 64) cur[tid] = blkBase[bid * 64 + tid];
    __syncthreads();
    const int r = bid * 256 + tid;
    const int s = sel[r];
    const int pos = atomicAdd(&cur[s], 1);
    rowsArr[pos] = r;
}

// ---------------- k_mlp: 1 wave per 64-row group; uniform weight loads (no readlane) ----
__global__ __launch_bounds__(64, 2) void k_mlp(
    const float* __restrict__ in,
    const float* __restrict__ w0, const float* __restrict__ b0,
    const float* __restrict__ w1, const float* __restrict__ b1,
    const float* __restrict__ w2, const float* __restrict__ b2,
    const float* __restrict__ w3, const float* __restrict__ b3,
    const float* __restrict__ w4, const float* __restrict__ b4,
    const int* __restrict__ gmodel, const int* __restrict__ rowsArr,
    float* __restrict__ out) {
    const int m = gmodel[blockIdx.x];
    if (m < 0) return;  // unused tail group
    const int lane = threadIdx.x;
    __shared__ float stage[64 * 66];   // per-lane slab, stride 66 -> 2-way bank alias (free)
    float* myst = stage + lane * 66;

    const int row = rowsArr[blockIdx.x * 64 + lane];
    const bool valid = row >= 0;
    const int r = valid ? row : 0;

    const float* xin = in + r * 6;
    const float x0 = xin[0], x1 = xin[1], x2 = xin[2];
    const float x3 = xin[3], x4 = xin[4], x5 = xin[5];

    float h[64];

    // ---- layer 0: 6 -> 64, fully unrolled (h[o] static), uniform weight loads ----
    {
        const float* W0 = w0 + m * 384;
        const float* B0 = b0 + m * 64;
#pragma unroll
        for (int o = 0; o < 64; ++o) {
            const float2 wa = *(const float2*)(W0 + o * 6);
            const float2 wb = *(const float2*)(W0 + o * 6 + 2);
            const float2 wc = *(const float2*)(W0 + o * 6 + 4);
            float a = B0[o];
            a = fmaf(wa.x, x0, a);
            a = fmaf(wa.y, x1, a);
            a = fmaf(wb.x, x2, a);
            a = fmaf(wb.y, x3, a);
            a = fmaf(wc.x, x4, a);
            a = fmaf(wc.y, x5, a);
            h[o] = fmaxf(a, 0.f);
        }
    }

    // ---- layers 1..3: 64 -> 64; uniform loads feed v_fmac directly ----
#pragma unroll 1
    for (int l = 0; l < 3; ++l) {
        const float* Wl = (l == 0 ? w1 : l == 1 ? w2 : w3) + m * 4096;
        const float* Bl = (l == 0 ? b1 : l == 1 ? b2 : b3) + m * 64;
#pragma unroll 4
        for (int o = 0; o < 64; ++o) {
            float a = Bl[o];
            const float4* wr = (const float4*)(Wl + o * 64);
#pragma unroll
            for (int q = 0; q < 16; ++q) {
                const float4 wv = wr[q];
                a = fmaf(wv.x, h[4 * q + 0], a);
                a = fmaf(wv.y, h[4 * q + 1], a);
                a = fmaf(wv.z, h[4 * q + 2], a);
                a = fmaf(wv.w, h[4 * q + 3], a);
            }
            myst[o] = fmaxf(a, 0.f);   // runtime-indexed -> LDS slab (not scratch)
        }
#pragma unroll
        for (int j = 0; j < 32; ++j) {
            const float2 t2 = *(const float2*)(myst + 2 * j);
            h[2 * j] = t2.x;
            h[2 * j + 1] = t2.y;
        }
    }

    // ---- layer 4: 64 -> 3 ----
    {
        const float* W4 = w4 + m * 192;
        float y[3];
#pragma unroll
        for (int c = 0; c < 3; ++c) {
            float a = b4[m * 3 + c];
            const float4* wr = (const float4*)(W4 + c * 64);
#pragma unroll
            for (int q = 0; q < 16; ++q) {
                const float4 wv = wr[q];
                a = fmaf(wv.x, h[4 * q + 0], a);
                a = fmaf(wv.y, h[4 * q + 1], a);
                a = fmaf(wv.z, h[4 * q + 2], a);
                a = fmaf(wv.w, h[4 * q + 3], a);
            }
            y[c] = a;
        }
        if (valid) {
            out[row * 3 + 0] = y[0];
            out[row * 3 + 1] = y[1];
            out[row * 3 + 2] = y[2];
            float* top = out + OUT_TOP;
            top[row * 3 + 0] = y[0];
            top[row * 3 + 1] = y[1];
            top[row * 3 + 2] = y[2];
        }
    }
}

extern "C" void kernel_launch(void* const* d_in, const int* in_sizes, int n_in,
                              void* d_out, int out_size, void* d_ws, size_t ws_size,
                              hipStream_t stream) {
    const float* in = (const float*)d_in[0];
    const float* w0 = (const float*)d_in[1];
    const float* b0 = (const float*)d_in[2];
    const float* w1 = (const float*)d_in[3];
    const float* b1 = (const float*)d_in[4];
    const float* w2 = (const float*)d_in[5];
    const float* b2 = (const float*)d_in[6];
    const float* w3 = (const float*)d_in[7];
    const float* b3 = (const float*)d_in[8];
    const float* w4 = (const float*)d_in[9];
    const float* b4 = (const float*)d_in[10];
    float* out = (float*)d_out;
    int* ws = (int*)d_ws;

    int* sel = ws + WS_SEL;
    int* blkCnt = ws + WS_BLK;
    int* rowsArr = ws + WS_ROWS;
    int* gmodel = ws + WS_GMOD;
    int* tot = ws + WS_TOT;

    // rowsArr (135168) + gmodel (2112) -> -1 ; tot (64) -> 0
    (void)hipMemsetAsync(rowsArr, 0xFF, (135168 + NGRP_MAX) * sizeof(int), stream);
    (void)hipMemsetAsync(tot, 0, 64 * sizeof(int), stream);

    k_prep<<<512, 256, 0, stream>>>(in, out, sel, blkCnt, tot);
    k_scanwrite<<<64, 64, 0, stream>>>(blkCnt, tot, gmodel);
    k_scatter<<<512, 256, 0, stream>>>(sel, blkCnt, rowsArr);
    k_mlp<<<NGRP_MAX, 64, 0, stream>>>(in, w0, b0, w1, b1, w2, b2, w3, b3,
                                       w4, b4, gmodel, rowsArr, out);
}

// Round 7
// 380.188 us; speedup vs baseline: 1.0536x; 1.0536x over previous
//
#include <hip/hip_runtime.h>
#include <hip/hip_bf16.h>

#define B_ROWS 131072
#define TWO_PI_F 6.28318530717958647692f

// Output layout (float32 element offsets into d_out):
#define OUT_TOP    393216
#define OUT_SEL    786432
#define OUT_LOGITS 917504
#define OUT_PROBS  9306112

// Workspace layout (int32 element offsets):
#define WS_SEL    0          // sel[131072]
#define WS_BLK    131072     // per-block hist -> scatter bases [512*64]
#define WS_ROWS   163840     // padded rowsArr[139264] (1088 groups * 128)
#define WS_GMOD   303104     // groupModel[1088]
#define WS_TOT    304192     // per-model totals [64]
#define NGRP2     1088       // max groups of 128 rows (1024 + 63 pad + slack)

typedef float vfloat4 __attribute__((ext_vector_type(4)));

// ---------------- k_prep: selection + per-block hist + totals + constant fills ----------
__global__ __launch_bounds__(256) void k_prep(const float* __restrict__ in,
                                              float* __restrict__ out,
                                              int* __restrict__ sel,
                                              int* __restrict__ blkCnt,
                                              int* __restrict__ tot) {
    __shared__ int hist[64];
    const int tid = threadIdx.x, bid = blockIdx.x;
    if (tid < 64) hist[tid] = 0;
    __syncthreads();

    const int r = bid * 256 + tid;  // grid exactly 512x256
    const float xx = in[r * 6 + 0];
    const float zz = in[r * 6 + 2];
    float a = atan2f(zz, xx);
    a = fmodf(a + TWO_PI_F, TWO_PI_F);
    const float t = a / TWO_PI_F * 64.0f;
    int s = (int)floorf(t);
    s = s < 0 ? 0 : (s > 63 ? 63 : s);
    sel[r] = s;
    out[OUT_SEL + r] = (float)s;
    atomicAdd(&hist[s], 1);

    {
        vfloat4* lg = (vfloat4*)(out + OUT_LOGITS);
        vfloat4* pb = (vfloat4*)(out + OUT_PROBS);
        const vfloat4 ones = {1.f, 1.f, 1.f, 1.f};
        const vfloat4 pr = {0.015625f, 0.015625f, 0.015625f, 0.015625f};
#pragma unroll
        for (int k = 0; k < 16; ++k) {
            __builtin_nontemporal_store(ones, lg + r + k * B_ROWS);
            __builtin_nontemporal_store(pr, pb + r + k * B_ROWS);
        }
    }

    __syncthreads();
    if (tid < 64) {
        blkCnt[bid * 64 + tid] = hist[tid];
        atomicAdd(&tot[tid], hist[tid]);
    }
}

// ---------------- k_scanwrite: 64 blocks; block bm owns model bm -----------------------
// Computes padded (128-row-group) bases, fills gmodel (incl. -1 tail), pad-fills rowsArr,
// and converts blkCnt counts -> per-(block,model) scatter bases. No memsets needed.
__global__ __launch_bounds__(64) void k_scanwrite(int* __restrict__ blkCnt,
                                                  const int* __restrict__ tot,
                                                  int* __restrict__ gmodel,
                                                  int* __restrict__ rowsArr) {
    const int lane = threadIdx.x;
    const int bm = blockIdx.x;

    const int t_l = tot[lane];
    const int grp_l = (t_l + 127) >> 7;
    int inc = grp_l;
#pragma unroll
    for (int off = 1; off < 64; off <<= 1) {
        const int n = __shfl_up(inc, off, 64);
        if (lane >= off) inc += n;
    }
    const int exg = inc - grp_l;
    const int offG = __shfl(exg, bm, 64);
    const int myGrp = __shfl(grp_l, bm, 64);
    const int myT = __shfl(t_l, bm, 64);
    const int totG = __shfl(inc, 63, 64);
    const int padBase = offG << 7;

    for (int i = lane; i < myGrp; i += 64) gmodel[offG + i] = bm;
    if (bm == 63) {
        for (int i = totG + lane; i < NGRP2; i += 64) gmodel[i] = -1;
    }
    for (int i = myT + lane; i < (myGrp << 7); i += 64) rowsArr[padBase + i] = -1;

    // segmented scan over 512 block-counts of model bm
    int c[8];
    int s = 0;
#pragma unroll
    for (int j = 0; j < 8; ++j) c[j] = blkCnt[(lane * 8 + j) * 64 + bm];
#pragma unroll
    for (int j = 0; j < 8; ++j) { const int v = c[j]; c[j] = s; s += v; }
    int incs = s;
#pragma unroll
    for (int off = 1; off < 64; off <<= 1) {
        const int n = __shfl_up(incs, off, 64);
        if (lane >= off) incs += n;
    }
    const int exs = incs - s;
#pragma unroll
    for (int j = 0; j < 8; ++j) blkCnt[(lane * 8 + j) * 64 + bm] = padBase + exs + c[j];
}

// ---------------- k_scatter: per-block reserved ranges, LDS atomics only ----------------
__global__ __launch_bounds__(256) void k_scatter(const int* __restrict__ sel,
                                                 const int* __restrict__ blkBase,
                                                 int* __restrict__ rowsArr) {
    __shared__ int cur[64];
    const int tid = threadIdx.x, bid = blockIdx.x;
    if (tid < 64) cur[tid] = blkBase[bid * 64 + tid];
    __syncthreads();
    const int r = bid * 256 + tid;
    const int s = sel[r];
    const int pos = atomicAdd(&cur[s], 1);
    rowsArr[pos] = r;
}

// ---- LDS layout for k_mlp2 (floats): WA[4096] | WB[4096] | W0p[512] | B0,B1,B2,B3[64ea]
//      | W4[192] | B4[4]  => 9156 floats = 36.6 KB -> 4 blocks/CU
#define L_WA  0
#define L_WB  4096
#define L_W0P 8192
#define L_B0  8704
#define L_B1  8768
#define L_B2  8832
#define L_B3  8896
#define L_W4  8960
#define L_B4  9152
#define L_TOT2 9156

__device__ __forceinline__ void loadW(float4 (&tmp)[16], const float* __restrict__ src,
                                      int lane) {
    const float4* s = (const float4*)src;
#pragma unroll
    for (int k = 0; k < 16; ++k) tmp[k] = s[lane + 64 * k];
}
__device__ __forceinline__ void writeW(float* dst, const float4 (&tmp)[16], int lane) {
    float4* d = (float4*)dst;
#pragma unroll
    for (int k = 0; k < 16; ++k) d[lane + 64 * k] = tmp[k];
}

// one 64->64 layer for two rows; h in VGPRs (static idx), g in scratch (dynamic idx)
__device__ __forceinline__ void layer64(const float* __restrict__ W,
                                        const float* __restrict__ Bv,
                                        const float (&h0)[64], const float (&h1)[64],
                                        float (&g0)[64], float (&g1)[64]) {
#pragma unroll 1
    for (int c = 0; c < 8; ++c) {
        float bb[8];
        *(float4*)&bb[0] = *(const float4*)(Bv + c * 8);
        *(float4*)&bb[4] = *(const float4*)(Bv + c * 8 + 4);
        const float* wc = W + c * 512;
#pragma unroll
        for (int u = 0; u < 8; ++u) {
            float a0 = bb[u], a1 = bb[u];
            const float4* wr = (const float4*)(wc + u * 64);
#pragma unroll
            for (int q = 0; q < 16; ++q) {
                const float4 wv = wr[q];
                a0 = fmaf(wv.x, h0[4 * q + 0], a0);
                a1 = fmaf(wv.x, h1[4 * q + 0], a1);
                a0 = fmaf(wv.y, h0[4 * q + 1], a0);
                a1 = fmaf(wv.y, h1[4 * q + 1], a1);
                a0 = fmaf(wv.z, h0[4 * q + 2], a0);
                a1 = fmaf(wv.z, h1[4 * q + 2], a1);
                a0 = fmaf(wv.w, h0[4 * q + 3], a0);
                a1 = fmaf(wv.w, h1[4 * q + 3], a1);
            }
            g0[c * 8 + u] = a0;
            g1[c * 8 + u] = a1;
        }
    }
}

__global__ __launch_bounds__(64, 1) void k_mlp2(
    const float* __restrict__ in,
    const float* __restrict__ w0, const float* __restrict__ b0,
    const float* __restrict__ w1, const float* __restrict__ b1,
    const float* __restrict__ w2, const float* __restrict__ b2,
    const float* __restrict__ w3, const float* __restrict__ b3,
    const float* __restrict__ w4, const float* __restrict__ b4,
    const int* __restrict__ gmodel, const int* __restrict__ rowsArr,
    float* __restrict__ out) {
    const int gidx = blockIdx.x;
    const int m = gmodel[gidx];
    if (m < 0) return;
    const int lane = threadIdx.x;
    __shared__ float lds[L_TOT2];

    const int row0 = rowsArr[gidx * 128 + lane];
    const int row1 = rowsArr[gidx * 128 + 64 + lane];
    const bool v0 = row0 >= 0, v1 = row1 >= 0;
    const int r0 = v0 ? row0 : 0, r1 = v1 ? row1 : 0;

    // W1 -> WA (issue loads first; write immediately — start-up latency only)
    float4 t1[16];
    loadW(t1, w1 + (size_t)m * 4096, lane);

    // small weights reg-stage
    {
        const float* s = w0 + m * 384 + lane * 6;
        float q0 = s[0], q1 = s[1], q2 = s[2], q3 = s[3], q4 = s[4], q5 = s[5];
        float* d = lds + L_W0P + lane * 8;
        d[0] = q0; d[1] = q1; d[2] = q2; d[3] = q3; d[4] = q4; d[5] = q5;
        lds[L_B0 + lane] = b0[m * 64 + lane];
        lds[L_B1 + lane] = b1[m * 64 + lane];
        lds[L_B2 + lane] = b2[m * 64 + lane];
        lds[L_B3 + lane] = b3[m * 64 + lane];
        lds[L_W4 + lane] = w4[m * 192 + lane];
        lds[L_W4 + 64 + lane] = w4[m * 192 + 64 + lane];
        lds[L_W4 + 128 + lane] = w4[m * 192 + 128 + lane];
        if (lane < 3) lds[L_B4 + lane] = b4[m * 3 + lane];
    }
    writeW(lds + L_WA, t1, lane);

    // inputs
    const float* xa = in + (size_t)r0 * 6;
    const float* xb = in + (size_t)r1 * 6;
    const float xa0 = xa[0], xa1 = xa[1], xa2 = xa[2], xa3 = xa[3], xa4 = xa[4], xa5 = xa[5];
    const float xb0 = xb[0], xb1 = xb[1], xb2 = xb[2], xb3 = xb[3], xb4 = xb[4], xb5 = xb[5];

    float h0[64], h1[64];
    float g0[64], g1[64];  // dynamic-indexed -> scratch (small, coalesced)

    // W2 loads issued before L0 compute; written to WB after
    float4 t2[16];
    loadW(t2, w2 + (size_t)m * 4096, lane);

    // ---- layer 0: 6 -> 64 ----
#pragma unroll 1
    for (int c = 0; c < 8; ++c) {
        float bb[8];
        *(float4*)&bb[0] = *(const float4*)(lds + L_B0 + c * 8);
        *(float4*)&bb[4] = *(const float4*)(lds + L_B0 + c * 8 + 4);
#pragma unroll
        for (int u = 0; u < 8; ++u) {
            const float* wr = lds + L_W0P + (c * 8 + u) * 8;
            const float4 wa = *(const float4*)(wr);
            const float2 wb = *(const float2*)(wr + 4);
            float a0 = bb[u], a1 = bb[u];
            a0 = fmaf(wa.x, xa0, a0); a1 = fmaf(wa.x, xb0, a1);
            a0 = fmaf(wa.y, xa1, a0); a1 = fmaf(wa.y, xb1, a1);
            a0 = fmaf(wa.z, xa2, a0); a1 = fmaf(wa.z, xb2, a1);
            a0 = fmaf(wa.w, xa3, a0); a1 = fmaf(wa.w, xb3, a1);
            a0 = fmaf(wb.x, xa4, a0); a1 = fmaf(wb.x, xb4, a1);
            a0 = fmaf(wb.y, xa5, a0); a1 = fmaf(wb.y, xb5, a1);
            g0[c * 8 + u] = a0;
            g1[c * 8 + u] = a1;
        }
    }
#pragma unroll
    for (int i = 0; i < 64; ++i) { h0[i] = fmaxf(g0[i], 0.f); h1[i] = fmaxf(g1[i], 0.f); }

    writeW(lds + L_WB, t2, lane);
    float4 t3[16];
    loadW(t3, w3 + (size_t)m * 4096, lane);

    // ---- layer 1 (reads WA) ----
    layer64(lds + L_WA, lds + L_B1, h0, h1, g0, g1);
#pragma unroll
    for (int i = 0; i < 64; ++i) { h0[i] = fmaxf(g0[i], 0.f); h1[i] = fmaxf(g1[i], 0.f); }

    writeW(lds + L_WA, t3, lane);  // W3 -> WA (WA retired)

    // ---- layer 2 (reads WB) ----
    layer64(lds + L_WB, lds + L_B2, h0, h1, g0, g1);
#pragma unroll
    for (int i = 0; i < 64; ++i) { h0[i] = fmaxf(g0[i], 0.f); h1[i] = fmaxf(g1[i], 0.f); }

    // ---- layer 3 (reads WA) ----
    layer64(lds + L_WA, lds + L_B3, h0, h1, g0, g1);
#pragma unroll
    for (int i = 0; i < 64; ++i) { h0[i] = fmaxf(g0[i], 0.f); h1[i] = fmaxf(g1[i], 0.f); }

    // ---- layer 4: 64 -> 3 ----
    float y0[3], y1[3];
#pragma unroll
    for (int c = 0; c < 3; ++c) {
        float a0 = lds[L_B4 + c], a1 = a0;
        const float4* wr = (const float4*)(lds + L_W4 + c * 64);
#pragma unroll
        for (int q = 0; q < 16; ++q) {
            const float4 wv = wr[q];
            a0 = fmaf(wv.x, h0[4 * q + 0], a0); a1 = fmaf(wv.x, h1[4 * q + 0], a1);
            a0 = fmaf(wv.y, h0[4 * q + 1], a0); a1 = fmaf(wv.y, h1[4 * q + 1], a1);
            a0 = fmaf(wv.z, h0[4 * q + 2], a0); a1 = fmaf(wv.z, h1[4 * q + 2], a1);
            a0 = fmaf(wv.w, h0[4 * q + 3], a0); a1 = fmaf(wv.w, h1[4 * q + 3], a1);
        }
        y0[c] = a0; y1[c] = a1;
    }
    float* top = out + OUT_TOP;
    if (v0) {
        out[row0 * 3 + 0] = y0[0]; out[row0 * 3 + 1] = y0[1]; out[row0 * 3 + 2] = y0[2];
        top[row0 * 3 + 0] = y0[0]; top[row0 * 3 + 1] = y0[1]; top[row0 * 3 + 2] = y0[2];
    }
    if (v1) {
        out[row1 * 3 + 0] = y1[0]; out[row1 * 3 + 1] = y1[1]; out[row1 * 3 + 2] = y1[2];
        top[row1 * 3 + 0] = y1[0]; top[row1 * 3 + 1] = y1[1]; top[row1 * 3 + 2] = y1[2];
    }
}

extern "C" void kernel_launch(void* const* d_in, const int* in_sizes, int n_in,
                              void* d_out, int out_size, void* d_ws, size_t ws_size,
                              hipStream_t stream) {
    const float* in = (const float*)d_in[0];
    const float* w0 = (const float*)d_in[1];
    const float* b0 = (const float*)d_in[2];
    const float* w1 = (const float*)d_in[3];
    const float* b1 = (const float*)d_in[4];
    const float* w2 = (const float*)d_in[5];
    const float* b2 = (const float*)d_in[6];
    const float* w3 = (const float*)d_in[7];
    const float* b3 = (const float*)d_in[8];
    const float* w4 = (const float*)d_in[9];
    const float* b4 = (const float*)d_in[10];
    float* out = (float*)d_out;
    int* ws = (int*)d_ws;

    int* sel = ws + WS_SEL;
    int* blkCnt = ws + WS_BLK;
    int* rowsArr = ws + WS_ROWS;
    int* gmodel = ws + WS_GMOD;
    int* tot = ws + WS_TOT;

    (void)hipMemsetAsync(tot, 0, 64 * sizeof(int), stream);

    k_prep<<<512, 256, 0, stream>>>(in, out, sel, blkCnt, tot);
    k_scanwrite<<<64, 64, 0, stream>>>(blkCnt, tot, gmodel, rowsArr);
    k_scatter<<<512, 256, 0, stream>>>(sel, blkCnt, rowsArr);
    k_mlp2<<<NGRP2, 64, 0, stream>>>(in, w0, b0, w1, b1, w2, b2, w3, b3,
                                     w4, b4, gmodel, rowsArr, out);
}

// Round 9
// 279.328 us; speedup vs baseline: 1.4341x; 1.3611x over previous
//
#include <hip/hip_runtime.h>
#include <hip/hip_bf16.h>

#define B_ROWS 131072
#define TWO_PI_F 6.28318530717958647692f

// Output layout (float32 element offsets into d_out):
#define OUT_TOP    393216
#define OUT_SEL    786432
#define OUT_LOGITS 917504
#define OUT_PROBS  9306112

// Workspace layout (int32 element offsets):
#define WS_SEL    0          // sel[131072]
#define WS_BLK    131072     // per-block hist -> scatter bases [512*64]
#define WS_ROWS   163840     // padded rowsArr[147456] (576 groups * 256)
#define WS_GMOD   311296     // groupModel[576]
#define WS_TOT    311872     // per-model totals [64]
#define NGRP3     576        // max groups of 256 rows (512 + 63 pad + slack)

// LDS float offsets for k_mlp3 (dynamic shared):
#define LW1   0
#define LW2   4096
#define LW3   8192
#define LW0   12288   // [64][8] padded rows
#define LB0   12800
#define LB1   12864
#define LB2   12928
#define LB3   12992
#define LW4   13056   // [3][64]
#define LB4   13248   // [3] (+1 pad)
#define LSLAB 13252   // slab[64][256] transposed: bank = tid%32, conflict-free
#define LTOT  (13252 + 64 * 256)          // 29636 floats
#define LDS_BYTES (LTOT * 4)              // 118544 B

typedef float vfloat4 __attribute__((ext_vector_type(4)));

// ---------------- k_prep: selection + per-block hist + totals + constant fills ----------
__global__ __launch_bounds__(256) void k_prep(const float* __restrict__ in,
                                              float* __restrict__ out,
                                              int* __restrict__ sel,
                                              int* __restrict__ blkCnt,
                                              int* __restrict__ tot) {
    __shared__ int hist[64];
    const int tid = threadIdx.x, bid = blockIdx.x;
    if (tid < 64) hist[tid] = 0;
    __syncthreads();

    const int r = bid * 256 + tid;  // grid exactly 512x256
    const float xx = in[r * 6 + 0];
    const float zz = in[r * 6 + 2];
    float a = atan2f(zz, xx);
    a = fmodf(a + TWO_PI_F, TWO_PI_F);
    const float t = a / TWO_PI_F * 64.0f;
    int s = (int)floorf(t);
    s = s < 0 ? 0 : (s > 63 ? 63 : s);
    sel[r] = s;
    out[OUT_SEL + r] = (float)s;
    atomicAdd(&hist[s], 1);

    {
        vfloat4* lg = (vfloat4*)(out + OUT_LOGITS);
        vfloat4* pb = (vfloat4*)(out + OUT_PROBS);
        const vfloat4 ones = {1.f, 1.f, 1.f, 1.f};
        const vfloat4 pr = {0.015625f, 0.015625f, 0.015625f, 0.015625f};
#pragma unroll
        for (int k = 0; k < 16; ++k) {
            __builtin_nontemporal_store(ones, lg + r + k * B_ROWS);
            __builtin_nontemporal_store(pr, pb + r + k * B_ROWS);
        }
    }

    __syncthreads();
    if (tid < 64) {
        blkCnt[bid * 64 + tid] = hist[tid];
        atomicAdd(&tot[tid], hist[tid]);
    }
}

// ---------------- k_scanwrite: 64 blocks; block bm owns model bm -----------------------
__global__ __launch_bounds__(64) void k_scanwrite(int* __restrict__ blkCnt,
                                                  const int* __restrict__ tot,
                                                  int* __restrict__ gmodel,
                                                  int* __restrict__ rowsArr) {
    const int lane = threadIdx.x;
    const int bm = blockIdx.x;

    const int t_l = tot[lane];
    const int grp_l = (t_l + 255) >> 8;
    int inc = grp_l;
#pragma unroll
    for (int off = 1; off < 64; off <<= 1) {
        const int n = __shfl_up(inc, off, 64);
        if (lane >= off) inc += n;
    }
    const int exg = inc - grp_l;
    const int offG = __shfl(exg, bm, 64);
    const int myGrp = __shfl(grp_l, bm, 64);
    const int myT = __shfl(t_l, bm, 64);
    const int totG = __shfl(inc, 63, 64);
    const int padBase = offG << 8;

    for (int i = lane; i < myGrp; i += 64) gmodel[offG + i] = bm;
    if (bm == 63) {
        for (int i = totG + lane; i < NGRP3; i += 64) gmodel[i] = -1;
    }
    for (int i = myT + lane; i < (myGrp << 8); i += 64) rowsArr[padBase + i] = -1;

    // segmented scan over 512 block-counts of model bm
    int c[8];
    int s = 0;
#pragma unroll
    for (int j = 0; j < 8; ++j) c[j] = blkCnt[(lane * 8 + j) * 64 + bm];
#pragma unroll
    for (int j = 0; j < 8; ++j) { const int v = c[j]; c[j] = s; s += v; }
    int incs = s;
#pragma unroll
    for (int off = 1; off < 64; off <<= 1) {
        const int n = __shfl_up(incs, off, 64);
        if (lane >= off) incs += n;
    }
    const int exs = incs - s;
#pragma unroll
    for (int j = 0; j < 8; ++j) blkCnt[(lane * 8 + j) * 64 + bm] = padBase + exs + c[j];
}

// ---------------- k_scatter: per-block reserved ranges, LDS atomics only ----------------
__global__ __launch_bounds__(256) void k_scatter(const int* __restrict__ sel,
                                                 const int* __restrict__ blkBase,
                                                 int* __restrict__ rowsArr) {
    __shared__ int cur[64];
    const int tid = threadIdx.x, bid = blockIdx.x;
    if (tid < 64) cur[tid] = blkBase[bid * 64 + tid];
    __syncthreads();
    const int r = bid * 256 + tid;
    const int s = sel[r];
    const int pos = atomicAdd(&cur[s], 1);
    rowsArr[pos] = r;
}

// one 64->64 layer: weights broadcast from LDS, h in VGPRs, handoff via transposed slab
__device__ __forceinline__ void layer_lds(const float* lds, int woff, int boff,
                                          float* slab, int tid, float (&h)[64]) {
#pragma unroll 2
    for (int op = 0; op < 32; ++op) {
        const int o0 = op * 2;
        const float* wr0 = lds + woff + o0 * 64;
        const float* wr1 = wr0 + 64;
        float a0 = lds[boff + o0];
        float a1 = lds[boff + o0 + 1];
        float c0 = 0.f, c1 = 0.f;
#pragma unroll
        for (int q = 0; q < 8; ++q) {
            const float4 w0a = ((const float4*)wr0)[q];
            const float4 w0b = ((const float4*)wr0)[q + 8];
            const float4 w1a = ((const float4*)wr1)[q];
            const float4 w1b = ((const float4*)wr1)[q + 8];
            a0 = fmaf(w0a.x, h[4 * q + 0], a0);
            a1 = fmaf(w1a.x, h[4 * q + 0], a1);
            c0 = fmaf(w0b.x, h[32 + 4 * q + 0], c0);
            c1 = fmaf(w1b.x, h[32 + 4 * q + 0], c1);
            a0 = fmaf(w0a.y, h[4 * q + 1], a0);
            a1 = fmaf(w1a.y, h[4 * q + 1], a1);
            c0 = fmaf(w0b.y, h[32 + 4 * q + 1], c0);
            c1 = fmaf(w1b.y, h[32 + 4 * q + 1], c1);
            a0 = fmaf(w0a.z, h[4 * q + 2], a0);
            a1 = fmaf(w1a.z, h[4 * q + 2], a1);
            c0 = fmaf(w0b.z, h[32 + 4 * q + 2], c0);
            c1 = fmaf(w1b.z, h[32 + 4 * q + 2], c1);
            a0 = fmaf(w0a.w, h[4 * q + 3], a0);
            a1 = fmaf(w1a.w, h[4 * q + 3], a1);
            c0 = fmaf(w0b.w, h[32 + 4 * q + 3], c0);
            c1 = fmaf(w1b.w, h[32 + 4 * q + 3], c1);
        }
        slab[o0 * 256 + tid] = fmaxf(a0 + c0, 0.f);
        slab[(o0 + 1) * 256 + tid] = fmaxf(a1 + c1, 0.f);
    }
#pragma unroll
    for (int j = 0; j < 64; ++j) h[j] = slab[j * 256 + tid];
}

__global__ __launch_bounds__(256, 1) void k_mlp3(
    const float* __restrict__ in,
    const float* __restrict__ w0, const float* __restrict__ b0,
    const float* __restrict__ w1, const float* __restrict__ b1,
    const float* __restrict__ w2, const float* __restrict__ b2,
    const float* __restrict__ w3, const float* __restrict__ b3,
    const float* __restrict__ w4, const float* __restrict__ b4,
    const int* __restrict__ gmodel, const int* __restrict__ rowsArr,
    float* __restrict__ out) {
    extern __shared__ float lds[];
    const int gidx = blockIdx.x;
    const int m = gmodel[gidx];
    if (m < 0) return;
    const int tid = threadIdx.x;
    float* slab = lds + LSLAB;

    // ---- stage all weights into LDS (coalesced float4 / scalars) ----
    {
        const float4* s1 = (const float4*)(w1 + (size_t)m * 4096);
        const float4* s2 = (const float4*)(w2 + (size_t)m * 4096);
        const float4* s3 = (const float4*)(w3 + (size_t)m * 4096);
        float4* d1 = (float4*)(lds + LW1);
        float4* d2 = (float4*)(lds + LW2);
        float4* d3 = (float4*)(lds + LW3);
#pragma unroll
        for (int k = 0; k < 4; ++k) {
            d1[tid + 256 * k] = s1[tid + 256 * k];
            d2[tid + 256 * k] = s2[tid + 256 * k];
            d3[tid + 256 * k] = s3[tid + 256 * k];
        }
        if (tid < 64) {
            const float* s0 = w0 + m * 384 + tid * 6;
            float* dd = lds + LW0 + tid * 8;
            dd[0] = s0[0]; dd[1] = s0[1]; dd[2] = s0[2];
            dd[3] = s0[3]; dd[4] = s0[4]; dd[5] = s0[5];
            lds[LB0 + tid] = b0[m * 64 + tid];
            lds[LB1 + tid] = b1[m * 64 + tid];
            lds[LB2 + tid] = b2[m * 64 + tid];
            lds[LB3 + tid] = b3[m * 64 + tid];
        }
        if (tid < 192) lds[LW4 + tid] = w4[m * 192 + tid];
        if (tid < 3) lds[LB4 + tid] = b4[m * 3 + tid];
    }
    __syncthreads();

    const int row = rowsArr[gidx * 256 + tid];
    const bool valid = row >= 0;
    const int r = valid ? row : 0;

    const float2 xv0 = *(const float2*)(in + (size_t)r * 6);
    const float2 xv1 = *(const float2*)(in + (size_t)r * 6 + 2);
    const float2 xv2 = *(const float2*)(in + (size_t)r * 6 + 4);
    const float x0 = xv0.x, x1 = xv0.y, x2 = xv1.x, x3 = xv1.y, x4 = xv2.x, x5 = xv2.y;

    float h[64];

    // ---- layer 0: 6 -> 64 via slab ----
#pragma unroll 4
    for (int op = 0; op < 32; ++op) {
        const int o0 = op * 2;
        const float4 wa0 = *(const float4*)(lds + LW0 + o0 * 8);
        const float2 wb0 = *(const float2*)(lds + LW0 + o0 * 8 + 4);
        const float4 wa1 = *(const float4*)(lds + LW0 + o0 * 8 + 8);
        const float2 wb1 = *(const float2*)(lds + LW0 + o0 * 8 + 12);
        float a0 = lds[LB0 + o0], a1 = lds[LB0 + o0 + 1];
        a0 = fmaf(wa0.x, x0, a0); a1 = fmaf(wa1.x, x0, a1);
        a0 = fmaf(wa0.y, x1, a0); a1 = fmaf(wa1.y, x1, a1);
        a0 = fmaf(wa0.z, x2, a0); a1 = fmaf(wa1.z, x2, a1);
        a0 = fmaf(wa0.w, x3, a0); a1 = fmaf(wa1.w, x3, a1);
        a0 = fmaf(wb0.x, x4, a0); a1 = fmaf(wb1.x, x4, a1);
        a0 = fmaf(wb0.y, x5, a0); a1 = fmaf(wb1.y, x5, a1);
        slab[o0 * 256 + tid] = fmaxf(a0, 0.f);
        slab[(o0 + 1) * 256 + tid] = fmaxf(a1, 0.f);
    }
#pragma unroll
    for (int j = 0; j < 64; ++j) h[j] = slab[j * 256 + tid];

    // ---- layers 1..3 ----
    layer_lds(lds, LW1, LB1, slab, tid, h);
    layer_lds(lds, LW2, LB2, slab, tid, h);
    layer_lds(lds, LW3, LB3, slab, tid, h);

    // ---- layer 4: 64 -> 3 (static, no slab) ----
    float y[3];
#pragma unroll
    for (int c = 0; c < 3; ++c) {
        const float* wr = lds + LW4 + c * 64;
        float a = lds[LB4 + c];
        float cc = 0.f;
#pragma unroll
        for (int q = 0; q < 8; ++q) {
            const float4 wv = ((const float4*)wr)[q];
            const float4 wv2 = ((const float4*)wr)[q + 8];
            a = fmaf(wv.x, h[4 * q + 0], a);
            cc = fmaf(wv2.x, h[32 + 4 * q + 0], cc);
            a = fmaf(wv.y, h[4 * q + 1], a);
            cc = fmaf(wv2.y, h[32 + 4 * q + 1], cc);
            a = fmaf(wv.z, h[4 * q + 2], a);
            cc = fmaf(wv2.z, h[32 + 4 * q + 2], cc);
            a = fmaf(wv.w, h[4 * q + 3], a);
            cc = fmaf(wv2.w, h[32 + 4 * q + 3], cc);
        }
        y[c] = a + cc;
    }
    if (valid) {
        out[row * 3 + 0] = y[0]; out[row * 3 + 1] = y[1]; out[row * 3 + 2] = y[2];
        float* top = out + OUT_TOP;
        top[row * 3 + 0] = y[0]; top[row * 3 + 1] = y[1]; top[row * 3 + 2] = y[2];
    }
}

extern "C" void kernel_launch(void* const* d_in, const int* in_sizes, int n_in,
                              void* d_out, int out_size, void* d_ws, size_t ws_size,
                              hipStream_t stream) {
    const float* in = (const float*)d_in[0];
    const float* w0 = (const float*)d_in[1];
    const float* b0 = (const float*)d_in[2];
    const float* w1 = (const float*)d_in[3];
    const float* b1 = (const float*)d_in[4];
    const float* w2 = (const float*)d_in[5];
    const float* b2 = (const float*)d_in[6];
    const float* w3 = (const float*)d_in[7];
    const float* b3 = (const float*)d_in[8];
    const float* w4 = (const float*)d_in[9];
    const float* b4 = (const float*)d_in[10];
    float* out = (float*)d_out;
    int* ws = (int*)d_ws;

    int* sel = ws + WS_SEL;
    int* blkCnt = ws + WS_BLK;
    int* rowsArr = ws + WS_ROWS;
    int* gmodel = ws + WS_GMOD;
    int* tot = ws + WS_TOT;

    (void)hipFuncSetAttribute(reinterpret_cast<const void*>(k_mlp3),
                              hipFuncAttributeMaxDynamicSharedMemorySize, LDS_BYTES);
    (void)hipMemsetAsync(tot, 0, 64 * sizeof(int), stream);

    k_prep<<<512, 256, 0, stream>>>(in, out, sel, blkCnt, tot);
    k_scanwrite<<<64, 64, 0, stream>>>(blkCnt, tot, gmodel, rowsArr);
    k_scatter<<<512, 256, 0, stream>>>(sel, blkCnt, rowsArr);
    k_mlp3<<<NGRP3, 256, LDS_BYTES, stream>>>(in, w0, b0, w1, b1, w2, b2, w3, b3,
                                              w4, b4, gmodel, rowsArr, out);
}